// Round 4
// baseline (1006.865 us; speedup 1.0000x reference)
//
#include <hip/hip_runtime.h>

// Problem constants (from reference setup_inputs)
#define FDIM 500
#define H1DIM 128
#define H2DIM 64
#define CDIM 10

using f32x4 = __attribute__((ext_vector_type(4))) float;
using bf16x8 = __attribute__((ext_vector_type(8))) short;  // 8 bf16 in 4 VGPRs

__device__ __forceinline__ unsigned short f32_to_bf16(float f) {
    unsigned u = __builtin_bit_cast(unsigned, f);
    u += 0x7FFFu + ((u >> 16) & 1u);  // RNE (inputs are finite, no NaN handling)
    return (unsigned short)(u >> 16);
}
__device__ __forceinline__ float bf16_to_f32(unsigned short h) {
    return __builtin_bit_cast(float, (unsigned)h << 16);
}
__device__ __forceinline__ float blo(unsigned u) {
    return __builtin_bit_cast(float, u << 16);
}
__device__ __forceinline__ float bhi(unsigned u) {
    return __builtin_bit_cast(float, u & 0xFFFF0000u);
}

// ---------------------------------------------------------------------------
// CSR build: histogram -> two-level scan -> atomic-cursor fill. dis = rsqrt(deg+1).
// fill also precomputes per-edge weight: ew[pos] = {src, dis[src]*dis[dst]}.
// ---------------------------------------------------------------------------

__global__ __launch_bounds__(256) void hist_kernel(const int* __restrict__ dst,
                                                   int* __restrict__ cnt, int E) {
    int e = blockIdx.x * 256 + threadIdx.x;
    if (e < E) atomicAdd(&cnt[dst[e]], 1);
}

__global__ __launch_bounds__(256) void dis_kernel(const int* __restrict__ cnt,
                                                  float* __restrict__ dis, int n) {
    int i = blockIdx.x * 256 + threadIdx.x;
    if (i < n) dis[i] = rsqrtf((float)cnt[i] + 1.0f);  // +1 self loop
}

__global__ __launch_bounds__(256) void block_reduce_kernel(const int* __restrict__ cnt,
                                                           int* __restrict__ bsums, int n) {
    __shared__ int s[256];
    int i = blockIdx.x * 256 + threadIdx.x;
    s[threadIdx.x] = (i < n) ? cnt[i] : 0;
    __syncthreads();
    for (int o = 128; o > 0; o >>= 1) {
        if (threadIdx.x < o) s[threadIdx.x] += s[threadIdx.x + o];
        __syncthreads();
    }
    if (threadIdx.x == 0) bsums[blockIdx.x] = s[0];
}

__global__ __launch_bounds__(512) void scan_sums_kernel(int* __restrict__ bsums, int nb,
                                                        int* __restrict__ row_ptr, int n) {
    __shared__ int s[512];
    int v = (threadIdx.x < nb) ? bsums[threadIdx.x] : 0;
    s[threadIdx.x] = v;
    __syncthreads();
    for (int o = 1; o < 512; o <<= 1) {
        int t = (threadIdx.x >= o) ? s[threadIdx.x - o] : 0;
        __syncthreads();
        s[threadIdx.x] += t;
        __syncthreads();
    }
    if (threadIdx.x < nb) bsums[threadIdx.x] = s[threadIdx.x] - v;  // exclusive
    if (threadIdx.x == 511) row_ptr[n] = s[511];                    // total == E
}

__global__ __launch_bounds__(256) void scan_blocks_kernel(const int* __restrict__ cnt,
                                                          const int* __restrict__ bsums,
                                                          int* __restrict__ row_ptr,
                                                          int* __restrict__ cursor, int n) {
    __shared__ int s[256];
    int i = blockIdx.x * 256 + threadIdx.x;
    int v = (i < n) ? cnt[i] : 0;
    s[threadIdx.x] = v;
    __syncthreads();
    for (int o = 1; o < 256; o <<= 1) {
        int t = (threadIdx.x >= o) ? s[threadIdx.x - o] : 0;
        __syncthreads();
        s[threadIdx.x] += t;
        __syncthreads();
    }
    int excl = s[threadIdx.x] - v + bsums[blockIdx.x];
    if (i < n) {
        row_ptr[i] = excl;
        cursor[i] = excl;
    }
}

__global__ __launch_bounds__(256) void fill_kernel(const int* __restrict__ src,
                                                   const int* __restrict__ dst,
                                                   const float* __restrict__ dis,
                                                   int* __restrict__ cursor,
                                                   int2* __restrict__ ew, int E) {
    int e = blockIdx.x * 256 + threadIdx.x;
    if (e < E) {
        int d = dst[e];
        int s = src[e];
        int pos = atomicAdd(&cursor[d], 1);
        float w = dis[s] * dis[d];
        ew[pos] = make_int2(s, __builtin_bit_cast(int, w));
    }
}

// ---------------------------------------------------------------------------
// Pre-pack W (fp32 [K,N]) into MFMA B-fragment layout, bf16, K zero-padded.
// ---------------------------------------------------------------------------
__global__ __launch_bounds__(256) void pack_w_kernel(const float* __restrict__ W,
                                                     unsigned short* __restrict__ Bp,
                                                     int K, int N, int T) {
    int idx = blockIdx.x * 256 + threadIdx.x;
    int NF = N >> 4;
    int total = T * NF * 64;
    if (idx >= total) return;
    int lane = idx & 63;
    int tnf = idx >> 6;
    int nf = tnf % NF;
    int t = tnf / NF;
    int kbase = t * 32 + (lane >> 4) * 8;
    int n = nf * 16 + (lane & 15);
    unsigned short v[8];
#pragma unroll
    for (int j = 0; j < 8; j++) {
        int k = kbase + j;
        float f = (k < K) ? W[(size_t)k * N + n] : 0.f;
        v[j] = f32_to_bf16(f);
    }
    uint4 p;
    p.x = (unsigned)v[0] | ((unsigned)v[1] << 16);
    p.y = (unsigned)v[2] | ((unsigned)v[3] << 16);
    p.z = (unsigned)v[4] | ((unsigned)v[5] << 16);
    p.w = (unsigned)v[6] | ((unsigned)v[7] << 16);
    *(uint4*)(Bp + (size_t)idx * 8) = p;
}

// ---------------------------------------------------------------------------
// LDS-free MFMA GEMM v2: 64 rows per wave (4 m-frags) -> 2x register B-reuse.
// CHUNKED epilogue writes C in 16-channel chunk-major slices
// (slice ch: [M rows x 16 ch] contiguous) so the aggregation pass can keep one
// 3.2 MB slice L2-resident per XCD. Same per-instruction write coalescing.
// ---------------------------------------------------------------------------
template <int NB, int K, bool ABF16, bool CHUNKED>
__global__ __launch_bounds__(64) void gemm_mfma(const void* __restrict__ Avoid,
                                                const unsigned short* __restrict__ Bp,
                                                unsigned short* __restrict__ C, int M) {
    constexpr int NF = NB / 16;
    constexpr int FULL = K / 32;
    constexpr int REM = K % 32;
    const int lane = threadIdx.x;
    const int quad = lane >> 4;
    const int mrow = lane & 15;
    const int m_base = blockIdx.x * 64;

    f32x4 acc[4][NF];
#pragma unroll
    for (int i = 0; i < 4; i++)
#pragma unroll
        for (int j = 0; j < NF; j++) acc[i][j] = (f32x4)(0.f);

    int c[4];
#pragma unroll
    for (int i = 0; i < 4; i++) c[i] = min(m_base + i * 16 + mrow, M - 1);  // stores guarded

    const float* Af = (const float*)Avoid;
    const unsigned short* Ah = (const unsigned short*)Avoid;

    for (int t = 0; t < FULL; t++) {
        const int k0 = t * 32 + quad * 8;
        bf16x8 a[4];
        if (ABF16) {
#pragma unroll
            for (int i = 0; i < 4; i++)
                a[i] = *(const bf16x8*)(Ah + (size_t)c[i] * K + k0);
        } else {
#pragma unroll
            for (int i = 0; i < 4; i++) {
                const float* p = Af + (size_t)c[i] * K + k0;
                float4 x = *(const float4*)p, y = *(const float4*)(p + 4);
                a[i][0] = (short)f32_to_bf16(x.x); a[i][1] = (short)f32_to_bf16(x.y);
                a[i][2] = (short)f32_to_bf16(x.z); a[i][3] = (short)f32_to_bf16(x.w);
                a[i][4] = (short)f32_to_bf16(y.x); a[i][5] = (short)f32_to_bf16(y.y);
                a[i][6] = (short)f32_to_bf16(y.z); a[i][7] = (short)f32_to_bf16(y.w);
            }
        }
#pragma unroll
        for (int nf = 0; nf < NF; nf++) {
            bf16x8 b = *(const bf16x8*)(Bp + (size_t)(t * NF + nf) * 512 + lane * 8);
#pragma unroll
            for (int i = 0; i < 4; i++)
                acc[i][nf] = __builtin_amdgcn_mfma_f32_16x16x32_bf16(a[i], b, acc[i][nf], 0, 0, 0);
        }
    }
    if constexpr (REM > 0) {  // K tail: guarded element loads, B tile zero-padded
        const int kb = FULL * 32 + quad * 8;
        bf16x8 a[4];
#pragma unroll
        for (int i = 0; i < 4; i++) {
#pragma unroll
            for (int j = 0; j < 8; j++) {
                int k = kb + j;
                float v = 0.f;
                if (k < K)
                    v = ABF16 ? bf16_to_f32(Ah[(size_t)c[i] * K + k]) : Af[(size_t)c[i] * K + k];
                a[i][j] = (short)f32_to_bf16(v);
            }
        }
#pragma unroll
        for (int nf = 0; nf < NF; nf++) {
            bf16x8 b = *(const bf16x8*)(Bp + (size_t)(FULL * NF + nf) * 512 + lane * 8);
#pragma unroll
            for (int i = 0; i < 4; i++)
                acc[i][nf] = __builtin_amdgcn_mfma_f32_16x16x32_bf16(a[i], b, acc[i][nf], 0, 0, 0);
        }
    }

    // epilogue: within m-frag i, D row = quad*4 + ii, col = nf*16 + mrow
#pragma unroll
    for (int i = 0; i < 4; i++)
#pragma unroll
        for (int ii = 0; ii < 4; ii++) {
            const int r = m_base + i * 16 + quad * 4 + ii;
            if (r < M) {
#pragma unroll
                for (int nf = 0; nf < NF; nf++) {
                    const size_t idx = CHUNKED ? ((size_t)nf * M + r) * 16 + mrow
                                               : (size_t)r * NB + nf * 16 + mrow;
                    C[idx] = f32_to_bf16(acc[i][nf][ii]);
                }
            }
        }
}

// ---------------------------------------------------------------------------
// Chunked aggregation v2: chunk-major 16-channel slices (100k x 32B = 3.2 MB,
// L2-resident per XCD; grid = (nodeblocks, chunk) with chunk the SLOW dim).
// Round-2 post-mortem: layout worked (FETCH == ideal cold fill) but the loop
// had MLP=1 (serial ew -> gather chain) -> latency-bound at 240us. v2 restores
// deep MLP: ONE node per wave, 16 edge slots x 4 lanes; per iteration all 16
// ew entries arrive in one coalesced 128B wave-load and all 16 row-gathers
// (independent 32B requests) are in flight at once. deg~16 -> typically one
// iteration; no intra-wave range divergence. ew stays nontemporal (evict-first
// keeps the slice resident; round-2 shows ew never reaches HBM).
// ---------------------------------------------------------------------------
template <int D, bool OUTBF16>
__global__ __launch_bounds__(256) void aggregate_chunked(const uint2* __restrict__ hc,
                                                         const float* __restrict__ dis,
                                                         const int* __restrict__ row_ptr,
                                                         const int2* __restrict__ ew,
                                                         const float* __restrict__ bias,
                                                         void* __restrict__ outv, int n) {
    const int lane = threadIdx.x & 63;
    const int wid = threadIdx.x >> 6;
    const int slot = lane >> 2;  // 16 edge slots per wave
    const int cpos = lane & 3;   // uint2 within the 32B chunk row-slice
    const int node = blockIdx.x * 4 + wid;
    const bool active = node < n;
    const int nc = active ? node : n - 1;
    const int ch = blockIdx.y;
    const uint2* slice = hc + (size_t)ch * n * 4;  // chunk slice, uint2 units

    const float di = dis[nc];
    const int beg = row_ptr[nc];
    const int end = active ? row_ptr[nc + 1] : beg;

    float ax0, ax1, ax2, ax3;
    {
        uint2 v = slice[(size_t)nc * 4 + cpos];
        float ws = (slot == 0) ? di * di : 0.f;  // self term counted once
        ax0 = ws * blo(v.x); ax1 = ws * bhi(v.x);
        ax2 = ws * blo(v.y); ax3 = ws * bhi(v.y);
    }
    for (int jb = beg; jb < end; jb += 16) {
        const int e = jb + slot;
        const bool ok = e < end;  // slot-uniform -> clean exec masking
        long long pe = __builtin_nontemporal_load((const long long*)ew + min(e, end - 1));
        const int s = (int)(unsigned)pe;
        const float w = ok ? __builtin_bit_cast(float, (int)(pe >> 32)) : 0.f;
        uint2 v = make_uint2(0u, 0u);
        if (ok) v = slice[(size_t)s * 4 + cpos];  // 16 independent 32B gathers in flight
        ax0 = fmaf(w, blo(v.x), ax0); ax1 = fmaf(w, bhi(v.x), ax1);
        ax2 = fmaf(w, blo(v.y), ax2); ax3 = fmaf(w, bhi(v.y), ax3);
    }
    // reduce across the 16 edge slots (lane bits 2..5)
    ax0 += __shfl_xor(ax0, 4); ax0 += __shfl_xor(ax0, 8);
    ax0 += __shfl_xor(ax0, 16); ax0 += __shfl_xor(ax0, 32);
    ax1 += __shfl_xor(ax1, 4); ax1 += __shfl_xor(ax1, 8);
    ax1 += __shfl_xor(ax1, 16); ax1 += __shfl_xor(ax1, 32);
    ax2 += __shfl_xor(ax2, 4); ax2 += __shfl_xor(ax2, 8);
    ax2 += __shfl_xor(ax2, 16); ax2 += __shfl_xor(ax2, 32);
    ax3 += __shfl_xor(ax3, 4); ax3 += __shfl_xor(ax3, 8);
    ax3 += __shfl_xor(ax3, 16); ax3 += __shfl_xor(ax3, 32);
    if (slot == 0 && active) {
        const float4 b = *(const float4*)(bias + ch * 16 + cpos * 4);
        const float r0 = fmaxf(ax0 + b.x, 0.f);
        const float r1 = fmaxf(ax1 + b.y, 0.f);
        const float r2 = fmaxf(ax2 + b.z, 0.f);
        const float r3 = fmaxf(ax3 + b.w, 0.f);
        if (OUTBF16) {
            uint2 r;
            r.x = (unsigned)f32_to_bf16(r0) | ((unsigned)f32_to_bf16(r1) << 16);
            r.y = (unsigned)f32_to_bf16(r2) | ((unsigned)f32_to_bf16(r3) << 16);
            ((uint2*)outv)[(size_t)node * (D / 4) + ch * 4 + cpos] = r;
        } else {
            float4 r;
            r.x = r0; r.y = r1; r.z = r2; r.w = r3;
            ((float4*)outv)[(size_t)node * (D / 4) + ch * 4 + cpos] = r;
        }
    }
}

// ---------------------------------------------------------------------------
// classifier: out[M x 10] = A[M x 64] * Wc[64 x 10] + bc. 16 threads/row.
// ---------------------------------------------------------------------------
__global__ __launch_bounds__(256) void classifier_kernel(const float* __restrict__ A,
                                                         const float* __restrict__ Wc,
                                                         const float* __restrict__ bc,
                                                         float* __restrict__ out, int M) {
    int idx = blockIdx.x * 256 + threadIdx.x;
    int row = idx >> 4;
    int c = idx & 15;
    if (row >= M || c >= CDIM) return;
    const float* a = A + (size_t)row * H2DIM;
    float acc = bc[c];
#pragma unroll 8
    for (int k = 0; k < H2DIM; k++) acc = fmaf(a[k], Wc[k * CDIM + c], acc);
    out[(size_t)row * CDIM + c] = acc;
}

// ---------------------------------------------------------------------------

extern "C" void kernel_launch(void* const* d_in, const int* in_sizes, int n_in,
                              void* d_out, int out_size, void* d_ws, size_t ws_size,
                              hipStream_t stream) {
    const float* x  = (const float*)d_in[0];
    const int*   ei = (const int*)d_in[1];
    const float* W1 = (const float*)d_in[2];
    const float* b1 = (const float*)d_in[3];
    const float* W2 = (const float*)d_in[4];
    const float* b2 = (const float*)d_in[5];
    const float* Wc = (const float*)d_in[6];
    const float* bc = (const float*)d_in[7];
    float* out = (float*)d_out;

    const int N = in_sizes[0] / FDIM;  // 100000
    const int E = in_sizes[1] / 2;     // 1600000
    const int* src = ei;
    const int* dst = ei + E;

    // workspace layout (bytes); agg2f overlays h1 (h1 dead after its aggregation)
    char* ws = (char*)d_ws;
    int*            cnt    = (int*)(ws + 0x000000);   // N ints (reused as cursor)
    int*            rowptr = (int*)(ws + 0x080000);   // N+1 ints
    float*          dis    = (float*)(ws + 0x100000); // N floats
    int*            bsums  = (int*)(ws + 0x180000);   // ceil(N/256) ints
    int2*           ew     = (int2*)(ws + 0x200000);  // E int2 (12.8 MB)
    unsigned short* W1p    = (unsigned short*)(ws + 0xE40000);  // 128 KB
    unsigned short* W2p    = (unsigned short*)(ws + 0xE80000);  // 16 KB
    unsigned short* h1     = (unsigned short*)(ws + 0xF00000);  // N*128 bf16, chunk-major (25.6 MB)
    float*          agg2f  = (float*)(ws + 0xF00000);           // N*64 fp32 (overlays h1)
    unsigned short* agg1   = (unsigned short*)(ws + 0x2800000); // N*128 bf16 row-major (25.6 MB)
    unsigned short* h2     = (unsigned short*)(ws + 0x4200000); // N*64 bf16, chunk-major (12.8 MB)

    const int nb = (N + 255) / 256;

    // 1. CSR build + dis + per-edge weights
    hipMemsetAsync(cnt, 0, (size_t)N * sizeof(int), stream);
    hist_kernel<<<(E + 255) / 256, 256, 0, stream>>>(dst, cnt, E);
    dis_kernel<<<nb, 256, 0, stream>>>(cnt, dis, N);
    block_reduce_kernel<<<nb, 256, 0, stream>>>(cnt, bsums, N);
    scan_sums_kernel<<<1, 512, 0, stream>>>(bsums, nb, rowptr, N);
    scan_blocks_kernel<<<nb, 256, 0, stream>>>(cnt, bsums, rowptr, /*cursor=*/cnt, N);
    fill_kernel<<<(E + 255) / 256, 256, 0, stream>>>(src, dst, dis, /*cursor=*/cnt, ew, E);

    // 2. pack weights to MFMA B-fragment bf16 layout
    pack_w_kernel<<<(16 * 8 * 64 + 255) / 256, 256, 0, stream>>>(W1, W1p, FDIM, H1DIM, 16);
    pack_w_kernel<<<(4 * 4 * 64 + 255) / 256, 256, 0, stream>>>(W2, W2p, H1DIM, H2DIM, 4);

    const int gblocks = (N + 63) / 64;  // GEMM: one wave / 64 rows
    const int ablocks = (N + 3) / 4;    // agg: 4 nodes (1/wave) per 256-thread block

    // 3. layer 1: GEMM writes h1 chunk-major; chunked agg -> agg1 row-major bf16
    gemm_mfma<H1DIM, FDIM, false, true><<<gblocks, 64, 0, stream>>>(x, W1p, h1, N);
    aggregate_chunked<H1DIM, true><<<dim3(ablocks, H1DIM / 16), 256, 0, stream>>>(
        (const uint2*)h1, dis, rowptr, ew, b1, agg1, N);

    // 4. layer 2: GEMM writes h2 chunk-major; chunked agg -> agg2f row-major fp32
    gemm_mfma<H2DIM, H1DIM, true, true><<<gblocks, 64, 0, stream>>>(agg1, W2p, h2, N);
    aggregate_chunked<H2DIM, false><<<dim3(ablocks, H2DIM / 16), 256, 0, stream>>>(
        (const uint2*)h2, dis, rowptr, ew, b2, agg2f, N);

    // 5. classifier
    classifier_kernel<<<(N * 16 + 255) / 256, 256, 0, stream>>>(agg2f, Wc, bc, out, N);
}

// Round 5
// 928.696 us; speedup vs baseline: 1.0842x; 1.0842x over previous
//
#include <hip/hip_runtime.h>

// Problem constants (from reference setup_inputs)
#define FDIM 500
#define H1DIM 128
#define H2DIM 64
#define CDIM 10

using f32x4 = __attribute__((ext_vector_type(4))) float;
using bf16x8 = __attribute__((ext_vector_type(8))) short;  // 8 bf16 in 4 VGPRs

__device__ __forceinline__ unsigned short f32_to_bf16(float f) {
    unsigned u = __builtin_bit_cast(unsigned, f);
    u += 0x7FFFu + ((u >> 16) & 1u);  // RNE (inputs are finite, no NaN handling)
    return (unsigned short)(u >> 16);
}
__device__ __forceinline__ float bf16_to_f32(unsigned short h) {
    return __builtin_bit_cast(float, (unsigned)h << 16);
}
__device__ __forceinline__ float blo(unsigned u) {
    return __builtin_bit_cast(float, u << 16);
}
__device__ __forceinline__ float bhi(unsigned u) {
    return __builtin_bit_cast(float, u & 0xFFFF0000u);
}

// ---------------------------------------------------------------------------
// CSR build: histogram -> two-level scan -> atomic-cursor fill. dis = rsqrt(deg+1).
// fill also precomputes per-edge weight: ew[pos] = {src, dis[src]*dis[dst]}.
// ---------------------------------------------------------------------------

__global__ __launch_bounds__(256) void hist_kernel(const int* __restrict__ dst,
                                                   int* __restrict__ cnt, int E) {
    int e = blockIdx.x * 256 + threadIdx.x;
    if (e < E) atomicAdd(&cnt[dst[e]], 1);
}

__global__ __launch_bounds__(256) void block_reduce_kernel(const int* __restrict__ cnt,
                                                           int* __restrict__ bsums, int n) {
    __shared__ int s[256];
    int i = blockIdx.x * 256 + threadIdx.x;
    s[threadIdx.x] = (i < n) ? cnt[i] : 0;
    __syncthreads();
    for (int o = 128; o > 0; o >>= 1) {
        if (threadIdx.x < o) s[threadIdx.x] += s[threadIdx.x + o];
        __syncthreads();
    }
    if (threadIdx.x == 0) bsums[blockIdx.x] = s[0];
}

__global__ __launch_bounds__(512) void scan_sums_kernel(int* __restrict__ bsums, int nb,
                                                        int* __restrict__ row_ptr, int n) {
    __shared__ int s[512];
    int v = (threadIdx.x < nb) ? bsums[threadIdx.x] : 0;
    s[threadIdx.x] = v;
    __syncthreads();
    for (int o = 1; o < 512; o <<= 1) {
        int t = (threadIdx.x >= o) ? s[threadIdx.x - o] : 0;
        __syncthreads();
        s[threadIdx.x] += t;
        __syncthreads();
    }
    if (threadIdx.x < nb) bsums[threadIdx.x] = s[threadIdx.x] - v;  // exclusive
    if (threadIdx.x == 511) row_ptr[n] = s[511];                    // total == E
}

// scan_blocks also computes dis = rsqrt(deg+1) (folds the old dis_kernel).
__global__ __launch_bounds__(256) void scan_blocks_kernel(const int* __restrict__ cnt,
                                                          const int* __restrict__ bsums,
                                                          int* __restrict__ row_ptr,
                                                          int* __restrict__ cursor,
                                                          float* __restrict__ dis, int n) {
    __shared__ int s[256];
    int i = blockIdx.x * 256 + threadIdx.x;
    int v = (i < n) ? cnt[i] : 0;
    s[threadIdx.x] = v;
    __syncthreads();
    for (int o = 1; o < 256; o <<= 1) {
        int t = (threadIdx.x >= o) ? s[threadIdx.x - o] : 0;
        __syncthreads();
        s[threadIdx.x] += t;
        __syncthreads();
    }
    int excl = s[threadIdx.x] - v + bsums[blockIdx.x];
    if (i < n) {
        row_ptr[i] = excl;
        cursor[i] = excl;
        dis[i] = rsqrtf((float)v + 1.0f);  // +1 self loop
    }
}

__global__ __launch_bounds__(256) void fill_kernel(const int* __restrict__ src,
                                                   const int* __restrict__ dst,
                                                   const float* __restrict__ dis,
                                                   int* __restrict__ cursor,
                                                   int2* __restrict__ ew, int E) {
    int e = blockIdx.x * 256 + threadIdx.x;
    if (e < E) {
        int d = dst[e];
        int s = src[e];
        int pos = atomicAdd(&cursor[d], 1);
        float w = dis[s] * dis[d];
        ew[pos] = make_int2(s, __builtin_bit_cast(int, w));
    }
}

// ---------------------------------------------------------------------------
// Pre-pack W (fp32 [K,N]) into MFMA B-fragment layout, bf16, K zero-padded.
// ---------------------------------------------------------------------------
__global__ __launch_bounds__(256) void pack_w_kernel(const float* __restrict__ W,
                                                     unsigned short* __restrict__ Bp,
                                                     int K, int N, int T) {
    int idx = blockIdx.x * 256 + threadIdx.x;
    int NF = N >> 4;
    int total = T * NF * 64;
    if (idx >= total) return;
    int lane = idx & 63;
    int tnf = idx >> 6;
    int nf = tnf % NF;
    int t = tnf / NF;
    int kbase = t * 32 + (lane >> 4) * 8;
    int n = nf * 16 + (lane & 15);
    unsigned short v[8];
#pragma unroll
    for (int j = 0; j < 8; j++) {
        int k = kbase + j;
        float f = (k < K) ? W[(size_t)k * N + n] : 0.f;
        v[j] = f32_to_bf16(f);
    }
    uint4 p;
    p.x = (unsigned)v[0] | ((unsigned)v[1] << 16);
    p.y = (unsigned)v[2] | ((unsigned)v[3] << 16);
    p.z = (unsigned)v[4] | ((unsigned)v[5] << 16);
    p.w = (unsigned)v[6] | ((unsigned)v[7] << 16);
    *(uint4*)(Bp + (size_t)idx * 8) = p;
}

// ---------------------------------------------------------------------------
// GEMM1 K-split x4: 256-thread block, 4 waves each own 4 of the 16 K-tiles for
// the SAME 64 rows; partials merged in LDS (32 KB) with atomicAdd, then a
// cooperative bf16 store. 4x the wave count of the old 64-thread version ->
// every SIMD keeps its residency slots full across the dispatch; the fp32->
// bf16 conversion VALU load is spread over 4 waves. A/B traffic unchanged.
// ---------------------------------------------------------------------------
template <int NB, int K>
__global__ __launch_bounds__(256) void gemm1_ksplit(const float* __restrict__ Af,
                                                    const unsigned short* __restrict__ Bp,
                                                    unsigned short* __restrict__ C, int M) {
    constexpr int NF = NB / 16;           // 8
    constexpr int TILES = (K + 31) / 32;  // 16 (last tile zero-padded in Bp)
    constexpr int FULL = K / 32;          // 15
    const int tid = threadIdx.x;
    const int w = tid >> 6;
    const int lane = tid & 63;
    const int quad = lane >> 4;
    const int mrow = lane & 15;
    const int m_base = blockIdx.x * 64;

    __shared__ float red[64 * NB];  // 32 KB fp32 accumulator
    for (int i = tid; i < 64 * NB; i += 256) red[i] = 0.f;

    f32x4 acc[4][NF];
#pragma unroll
    for (int i = 0; i < 4; i++)
#pragma unroll
        for (int j = 0; j < NF; j++) acc[i][j] = (f32x4)(0.f);

    int c[4];
#pragma unroll
    for (int i = 0; i < 4; i++) c[i] = min(m_base + i * 16 + mrow, M - 1);  // stores guarded

    const int t0 = w * (TILES / 4);
    const int t1 = t0 + TILES / 4;
    __syncthreads();  // red zero-init visible before any atomicAdd

    for (int t = t0; t < t1; t++) {
        const int k0 = t * 32 + quad * 8;
        bf16x8 a[4];
        if (t < FULL) {
#pragma unroll
            for (int i = 0; i < 4; i++) {
                const float* p = Af + (size_t)c[i] * K + k0;
                float4 x = *(const float4*)p, y = *(const float4*)(p + 4);
                a[i][0] = (short)f32_to_bf16(x.x); a[i][1] = (short)f32_to_bf16(x.y);
                a[i][2] = (short)f32_to_bf16(x.z); a[i][3] = (short)f32_to_bf16(x.w);
                a[i][4] = (short)f32_to_bf16(y.x); a[i][5] = (short)f32_to_bf16(y.y);
                a[i][6] = (short)f32_to_bf16(y.z); a[i][7] = (short)f32_to_bf16(y.w);
            }
        } else {  // zero-padded K tail (only the last wave sees this)
#pragma unroll
            for (int i = 0; i < 4; i++) {
#pragma unroll
                for (int j = 0; j < 8; j++) {
                    int k = k0 + j;
                    float v = (k < K) ? Af[(size_t)c[i] * K + k] : 0.f;
                    a[i][j] = (short)f32_to_bf16(v);
                }
            }
        }
#pragma unroll
        for (int nf = 0; nf < NF; nf++) {
            bf16x8 b = *(const bf16x8*)(Bp + (size_t)(t * NF + nf) * 512 + lane * 8);
#pragma unroll
            for (int i = 0; i < 4; i++)
                acc[i][nf] = __builtin_amdgcn_mfma_f32_16x16x32_bf16(a[i], b, acc[i][nf], 0, 0, 0);
        }
    }

    // merge partials: D row = quad*4+ii within m-frag i, col = nf*16+mrow
#pragma unroll
    for (int i = 0; i < 4; i++)
#pragma unroll
        for (int ii = 0; ii < 4; ii++) {
            const int rl = i * 16 + quad * 4 + ii;
#pragma unroll
            for (int nf = 0; nf < NF; nf++)
                atomicAdd(&red[rl * NB + nf * 16 + mrow], acc[i][nf][ii]);
        }
    __syncthreads();

    // cooperative store: 64*NB/8 uint4 groups, fully coalesced
    constexpr int GPR = NB / 8;  // groups per row
    for (int g = tid; g < 64 * GPR; g += 256) {
        const int row = g / GPR;
        const int c8 = (g % GPR) * 8;
        const int r = m_base + row;
        if (r < M) {
            const float* src = red + row * NB + c8;
            unsigned short v[8];
#pragma unroll
            for (int j = 0; j < 8; j++) v[j] = f32_to_bf16(src[j]);
            uint4 p;
            p.x = (unsigned)v[0] | ((unsigned)v[1] << 16);
            p.y = (unsigned)v[2] | ((unsigned)v[3] << 16);
            p.z = (unsigned)v[4] | ((unsigned)v[5] << 16);
            p.w = (unsigned)v[6] | ((unsigned)v[7] << 16);
            *(uint4*)(C + (size_t)r * NB + c8) = p;
        }
    }
}

// ---------------------------------------------------------------------------
// LDS-free MFMA GEMM (round-0 form): 64 rows per wave (4 m-frags), one wave
// per 64-thread block. Used for layer 2 (K=128, A already bf16).
// ---------------------------------------------------------------------------
template <int NB, int K, bool ABF16>
__global__ __launch_bounds__(64) void gemm_mfma(const void* __restrict__ Avoid,
                                                const unsigned short* __restrict__ Bp,
                                                unsigned short* __restrict__ C, int M) {
    constexpr int NF = NB / 16;
    constexpr int FULL = K / 32;
    constexpr int REM = K % 32;
    const int lane = threadIdx.x;
    const int quad = lane >> 4;
    const int mrow = lane & 15;
    const int m_base = blockIdx.x * 64;

    f32x4 acc[4][NF];
#pragma unroll
    for (int i = 0; i < 4; i++)
#pragma unroll
        for (int j = 0; j < NF; j++) acc[i][j] = (f32x4)(0.f);

    int c[4];
#pragma unroll
    for (int i = 0; i < 4; i++) c[i] = min(m_base + i * 16 + mrow, M - 1);  // stores guarded

    const float* Af = (const float*)Avoid;
    const unsigned short* Ah = (const unsigned short*)Avoid;

    for (int t = 0; t < FULL; t++) {
        const int k0 = t * 32 + quad * 8;
        bf16x8 a[4];
        if (ABF16) {
#pragma unroll
            for (int i = 0; i < 4; i++)
                a[i] = *(const bf16x8*)(Ah + (size_t)c[i] * K + k0);
        } else {
#pragma unroll
            for (int i = 0; i < 4; i++) {
                const float* p = Af + (size_t)c[i] * K + k0;
                float4 x = *(const float4*)p, y = *(const float4*)(p + 4);
                a[i][0] = (short)f32_to_bf16(x.x); a[i][1] = (short)f32_to_bf16(x.y);
                a[i][2] = (short)f32_to_bf16(x.z); a[i][3] = (short)f32_to_bf16(x.w);
                a[i][4] = (short)f32_to_bf16(y.x); a[i][5] = (short)f32_to_bf16(y.y);
                a[i][6] = (short)f32_to_bf16(y.z); a[i][7] = (short)f32_to_bf16(y.w);
            }
        }
#pragma unroll
        for (int nf = 0; nf < NF; nf++) {
            bf16x8 b = *(const bf16x8*)(Bp + (size_t)(t * NF + nf) * 512 + lane * 8);
#pragma unroll
            for (int i = 0; i < 4; i++)
                acc[i][nf] = __builtin_amdgcn_mfma_f32_16x16x32_bf16(a[i], b, acc[i][nf], 0, 0, 0);
        }
    }
    if constexpr (REM > 0) {  // K tail: guarded element loads, B tile zero-padded
        const int kb = FULL * 32 + quad * 8;
        bf16x8 a[4];
#pragma unroll
        for (int i = 0; i < 4; i++) {
#pragma unroll
            for (int j = 0; j < 8; j++) {
                int k = kb + j;
                float v = 0.f;
                if (k < K)
                    v = ABF16 ? bf16_to_f32(Ah[(size_t)c[i] * K + k]) : Af[(size_t)c[i] * K + k];
                a[i][j] = (short)f32_to_bf16(v);
            }
        }
#pragma unroll
        for (int nf = 0; nf < NF; nf++) {
            bf16x8 b = *(const bf16x8*)(Bp + (size_t)(FULL * NF + nf) * 512 + lane * 8);
#pragma unroll
            for (int i = 0; i < 4; i++)
                acc[i][nf] = __builtin_amdgcn_mfma_f32_16x16x32_bf16(a[i], b, acc[i][nf], 0, 0, 0);
        }
    }

    // epilogue: within m-frag i, D row = quad*4 + ii, col = nf*16 + mrow
#pragma unroll
    for (int i = 0; i < 4; i++)
#pragma unroll
        for (int ii = 0; ii < 4; ii++) {
            const int r = m_base + i * 16 + quad * 4 + ii;
            if (r < M) {
#pragma unroll
                for (int nf = 0; nf < NF; nf++)
                    C[(size_t)r * NB + nf * 16 + mrow] = f32_to_bf16(acc[i][nf][ii]);
            }
        }
}

// ---------------------------------------------------------------------------
// Aggregation v3 (round-0 form, D=128, bf16->bf16): one wave/node, half-wave
// per edge, 16 edges/step: 8 contiguous ew loads in flight, then exec-masked
// row gathers (masked tail halves skip the fetch -> no padding BW waste).
// ---------------------------------------------------------------------------
__global__ __launch_bounds__(256) void aggregate128_v3(const uint2* __restrict__ h,
                                                       const float* __restrict__ dis,
                                                       const int* __restrict__ row_ptr,
                                                       const int2* __restrict__ ew,
                                                       const float* __restrict__ bias,
                                                       uint2* __restrict__ out, int n) {
    const int node = blockIdx.x * 4 + (threadIdx.x >> 6);
    if (node >= n) return;
    const int lane = threadIdx.x & 63;
    const int half = lane >> 5;
    const int c = lane & 31;  // uint2 index in row; channels 4c..4c+3
    const float di = dis[node];
    const int beg = row_ptr[node], end = row_ptr[node + 1];

    float ax0, ax1, ax2, ax3;
    {
        uint2 v = h[(size_t)node * 32 + c];
        float ws = half ? 0.f : di * di;  // self term counted once
        ax0 = ws * blo(v.x); ax1 = ws * bhi(v.x);
        ax2 = ws * blo(v.y); ax3 = ws * bhi(v.y);
    }
    for (int jb = beg; jb < end; jb += 16) {
        int2 p[8];
#pragma unroll
        for (int u = 0; u < 8; u++)
            p[u] = ew[min(jb + half + 2 * u, end - 1)];  // contiguous 8B, tail dup harmless
        float w[8];
        uint2 v[8];
#pragma unroll
        for (int u = 0; u < 8; u++) {
            const bool ok = (jb + half + 2 * u) < end;  // half-uniform -> exec-masked load
            w[u] = ok ? __builtin_bit_cast(float, p[u].y) : 0.f;
            if (ok) v[u] = h[(size_t)p[u].x * 32 + c];
            else    v[u] = make_uint2(0u, 0u);
        }
#pragma unroll
        for (int u = 0; u < 8; u++) {
            ax0 = fmaf(w[u], blo(v[u].x), ax0); ax1 = fmaf(w[u], bhi(v[u].x), ax1);
            ax2 = fmaf(w[u], blo(v[u].y), ax2); ax3 = fmaf(w[u], bhi(v[u].y), ax3);
        }
    }
    ax0 += __shfl_xor(ax0, 32);
    ax1 += __shfl_xor(ax1, 32);
    ax2 += __shfl_xor(ax2, 32);
    ax3 += __shfl_xor(ax3, 32);
    if (half == 0) {
        const float4 b = *(const float4*)(bias + 4 * c);
        uint2 r;
        r.x = (unsigned)f32_to_bf16(fmaxf(ax0 + b.x, 0.f)) |
              ((unsigned)f32_to_bf16(fmaxf(ax1 + b.y, 0.f)) << 16);
        r.y = (unsigned)f32_to_bf16(fmaxf(ax2 + b.z, 0.f)) |
              ((unsigned)f32_to_bf16(fmaxf(ax3 + b.w, 0.f)) << 16);
        out[(size_t)node * 32 + c] = r;
    }
}

// ---------------------------------------------------------------------------
// Aggregation v3 (D=64) with FUSED classifier: after the shuffle reduction the
// post-ReLU 64-ch row is staged in LDS (1 KB/block); lanes 0..9 of each wave
// then compute out[node][cls] = row . Wc[:,cls] + bc directly. Removes the
// separate classifier dispatch and the 51 MB agg2f write+read round-trip.
// NO early return (barrier below); N divisible by 4 so all waves active anyway.
// ---------------------------------------------------------------------------
__global__ __launch_bounds__(256) void aggregate64_cls(const uint2* __restrict__ h,
                                                       const float* __restrict__ dis,
                                                       const int* __restrict__ row_ptr,
                                                       const int2* __restrict__ ew,
                                                       const float* __restrict__ bias,
                                                       const float* __restrict__ Wc,
                                                       const float* __restrict__ bc,
                                                       float* __restrict__ out, int n) {
    __shared__ float sm[4][H2DIM];
    const int wid = threadIdx.x >> 6;
    const int lane = threadIdx.x & 63;
    const int quad = lane >> 4;
    const int c = lane & 15;  // uint2 index in row; channels 4c..4c+3
    const int node = blockIdx.x * 4 + wid;
    const bool active = node < n;
    const int nc = active ? node : n - 1;
    const float di = dis[nc];
    const int beg = row_ptr[nc];
    const int end = active ? row_ptr[nc + 1] : beg;

    float ax0, ax1, ax2, ax3;
    {
        uint2 v = h[(size_t)nc * 16 + c];
        float ws = quad ? 0.f : di * di;
        ax0 = ws * blo(v.x); ax1 = ws * bhi(v.x);
        ax2 = ws * blo(v.y); ax3 = ws * bhi(v.y);
    }
    for (int jb = beg; jb < end; jb += 16) {
        int2 p[4];
#pragma unroll
        for (int u = 0; u < 4; u++)
            p[u] = ew[min(jb + quad + 4 * u, end - 1)];
        float w[4];
        uint2 v[4];
#pragma unroll
        for (int u = 0; u < 4; u++) {
            const bool ok = (jb + quad + 4 * u) < end;  // quad-uniform
            w[u] = ok ? __builtin_bit_cast(float, p[u].y) : 0.f;
            if (ok) v[u] = h[(size_t)p[u].x * 16 + c];
            else    v[u] = make_uint2(0u, 0u);
        }
#pragma unroll
        for (int u = 0; u < 4; u++) {
            ax0 = fmaf(w[u], blo(v[u].x), ax0); ax1 = fmaf(w[u], bhi(v[u].x), ax1);
            ax2 = fmaf(w[u], blo(v[u].y), ax2); ax3 = fmaf(w[u], bhi(v[u].y), ax3);
        }
    }
    ax0 += __shfl_xor(ax0, 16); ax0 += __shfl_xor(ax0, 32);
    ax1 += __shfl_xor(ax1, 16); ax1 += __shfl_xor(ax1, 32);
    ax2 += __shfl_xor(ax2, 16); ax2 += __shfl_xor(ax2, 32);
    ax3 += __shfl_xor(ax3, 16); ax3 += __shfl_xor(ax3, 32);
    if (lane < 16) {
        const float4 b = *(const float4*)(bias + 4 * c);
        sm[wid][4 * c + 0] = fmaxf(ax0 + b.x, 0.f);
        sm[wid][4 * c + 1] = fmaxf(ax1 + b.y, 0.f);
        sm[wid][4 * c + 2] = fmaxf(ax2 + b.z, 0.f);
        sm[wid][4 * c + 3] = fmaxf(ax3 + b.w, 0.f);
    }
    __syncthreads();
    if (active && lane < CDIM) {
        float a2 = bc[lane];
#pragma unroll 8
        for (int k = 0; k < H2DIM; k++) a2 = fmaf(sm[wid][k], Wc[k * CDIM + lane], a2);
        out[(size_t)node * CDIM + lane] = a2;
    }
}

// ---------------------------------------------------------------------------

extern "C" void kernel_launch(void* const* d_in, const int* in_sizes, int n_in,
                              void* d_out, int out_size, void* d_ws, size_t ws_size,
                              hipStream_t stream) {
    const float* x  = (const float*)d_in[0];
    const int*   ei = (const int*)d_in[1];
    const float* W1 = (const float*)d_in[2];
    const float* b1 = (const float*)d_in[3];
    const float* W2 = (const float*)d_in[4];
    const float* b2 = (const float*)d_in[5];
    const float* Wc = (const float*)d_in[6];
    const float* bc = (const float*)d_in[7];
    float* out = (float*)d_out;

    const int N = in_sizes[0] / FDIM;  // 100000
    const int E = in_sizes[1] / 2;     // 1600000
    const int* src = ei;
    const int* dst = ei + E;

    // workspace layout (bytes)
    char* ws = (char*)d_ws;
    int*            cnt    = (int*)(ws + 0x000000);   // N ints (reused as cursor)
    int*            rowptr = (int*)(ws + 0x080000);   // N+1 ints
    float*          dis    = (float*)(ws + 0x100000); // N floats
    int*            bsums  = (int*)(ws + 0x180000);   // ceil(N/256) ints
    int2*           ew     = (int2*)(ws + 0x200000);  // E int2 (12.8 MB)
    unsigned short* W1p    = (unsigned short*)(ws + 0xE40000);  // 128 KB
    unsigned short* W2p    = (unsigned short*)(ws + 0xE80000);  // 16 KB
    unsigned short* h1     = (unsigned short*)(ws + 0xF00000);  // N*128 bf16 (25.6 MB)
    unsigned short* agg1   = (unsigned short*)(ws + 0x2800000); // N*128 bf16 (25.6 MB)
    unsigned short* h2     = (unsigned short*)(ws + 0x4200000); // N*64 bf16 (12.8 MB)

    const int nb = (N + 255) / 256;

    // 1. CSR build + dis + per-edge weights
    hipMemsetAsync(cnt, 0, (size_t)N * sizeof(int), stream);
    hist_kernel<<<(E + 255) / 256, 256, 0, stream>>>(dst, cnt, E);
    block_reduce_kernel<<<nb, 256, 0, stream>>>(cnt, bsums, N);
    scan_sums_kernel<<<1, 512, 0, stream>>>(bsums, nb, rowptr, N);
    scan_blocks_kernel<<<nb, 256, 0, stream>>>(cnt, bsums, rowptr, /*cursor=*/cnt, dis, N);
    fill_kernel<<<(E + 255) / 256, 256, 0, stream>>>(src, dst, dis, /*cursor=*/cnt, ew, E);

    // 2. pack weights to MFMA B-fragment bf16 layout
    pack_w_kernel<<<(16 * 8 * 64 + 255) / 256, 256, 0, stream>>>(W1, W1p, FDIM, H1DIM, 16);
    pack_w_kernel<<<(4 * 4 * 64 + 255) / 256, 256, 0, stream>>>(W2, W2p, H1DIM, H2DIM, 4);

    const int gblocks = (N + 63) / 64;  // 1563 row-blocks of 64

    // 3. layer 1: K-split GEMM (4 waves/block) -> agg (+ReLU+bias)
    gemm1_ksplit<H1DIM, FDIM><<<gblocks, 256, 0, stream>>>(x, W1p, h1, N);
    aggregate128_v3<<<(N + 3) / 4, 256, 0, stream>>>((const uint2*)h1, dis, rowptr, ew, b1,
                                                     (uint2*)agg1, N);
    // 4. layer 2: GEMM -> agg (+ReLU+bias) with fused classifier
    gemm_mfma<H2DIM, H1DIM, true><<<gblocks, 64, 0, stream>>>(agg1, W2p, h2, N);
    aggregate64_cls<<<(N + 3) / 4, 256, 0, stream>>>((const uint2*)h2, dis, rowptr, ew, b2,
                                                     Wc, bc, out, N);
}

// Round 6
// 646.968 us; speedup vs baseline: 1.5563x; 1.4355x over previous
//
#include <hip/hip_runtime.h>

// Problem constants (from reference setup_inputs)
#define FDIM 500
#define H1DIM 128
#define H2DIM 64
#define CDIM 10

using f32x4 = __attribute__((ext_vector_type(4))) float;
using bf16x8 = __attribute__((ext_vector_type(8))) short;  // 8 bf16 in 4 VGPRs

__device__ __forceinline__ unsigned short f32_to_bf16(float f) {
    unsigned u = __builtin_bit_cast(unsigned, f);
    u += 0x7FFFu + ((u >> 16) & 1u);  // RNE (inputs are finite, no NaN handling)
    return (unsigned short)(u >> 16);
}
__device__ __forceinline__ float bf16_to_f32(unsigned short h) {
    return __builtin_bit_cast(float, (unsigned)h << 16);
}
__device__ __forceinline__ float blo(unsigned u) {
    return __builtin_bit_cast(float, u << 16);
}
__device__ __forceinline__ float bhi(unsigned u) {
    return __builtin_bit_cast(float, u & 0xFFFF0000u);
}

// ---------------------------------------------------------------------------
// CSR build: histogram -> two-level scan -> atomic-cursor fill. dis = rsqrt(deg+1)
// folded into scan_blocks. fill precomputes ew[pos] = {src, dis[src]*dis[dst]}.
// ---------------------------------------------------------------------------

__global__ __launch_bounds__(256) void hist_kernel(const int* __restrict__ dst,
                                                   int* __restrict__ cnt, int E) {
    int e = blockIdx.x * 256 + threadIdx.x;
    if (e < E) atomicAdd(&cnt[dst[e]], 1);
}

__global__ __launch_bounds__(256) void block_reduce_kernel(const int* __restrict__ cnt,
                                                           int* __restrict__ bsums, int n) {
    __shared__ int s[256];
    int i = blockIdx.x * 256 + threadIdx.x;
    s[threadIdx.x] = (i < n) ? cnt[i] : 0;
    __syncthreads();
    for (int o = 128; o > 0; o >>= 1) {
        if (threadIdx.x < o) s[threadIdx.x] += s[threadIdx.x + o];
        __syncthreads();
    }
    if (threadIdx.x == 0) bsums[blockIdx.x] = s[0];
}

__global__ __launch_bounds__(512) void scan_sums_kernel(int* __restrict__ bsums, int nb,
                                                        int* __restrict__ row_ptr, int n) {
    __shared__ int s[512];
    int v = (threadIdx.x < nb) ? bsums[threadIdx.x] : 0;
    s[threadIdx.x] = v;
    __syncthreads();
    for (int o = 1; o < 512; o <<= 1) {
        int t = (threadIdx.x >= o) ? s[threadIdx.x - o] : 0;
        __syncthreads();
        s[threadIdx.x] += t;
        __syncthreads();
    }
    if (threadIdx.x < nb) bsums[threadIdx.x] = s[threadIdx.x] - v;  // exclusive
    if (threadIdx.x == 511) row_ptr[n] = s[511];                    // total == E
}

// scan_blocks also computes dis = rsqrt(deg+1) (folds the old dis_kernel).
__global__ __launch_bounds__(256) void scan_blocks_kernel(const int* __restrict__ cnt,
                                                          const int* __restrict__ bsums,
                                                          int* __restrict__ row_ptr,
                                                          int* __restrict__ cursor,
                                                          float* __restrict__ dis, int n) {
    __shared__ int s[256];
    int i = blockIdx.x * 256 + threadIdx.x;
    int v = (i < n) ? cnt[i] : 0;
    s[threadIdx.x] = v;
    __syncthreads();
    for (int o = 1; o < 256; o <<= 1) {
        int t = (threadIdx.x >= o) ? s[threadIdx.x - o] : 0;
        __syncthreads();
        s[threadIdx.x] += t;
        __syncthreads();
    }
    int excl = s[threadIdx.x] - v + bsums[blockIdx.x];
    if (i < n) {
        row_ptr[i] = excl;
        cursor[i] = excl;
        dis[i] = rsqrtf((float)v + 1.0f);  // +1 self loop
    }
}

__global__ __launch_bounds__(256) void fill_kernel(const int* __restrict__ src,
                                                   const int* __restrict__ dst,
                                                   const float* __restrict__ dis,
                                                   int* __restrict__ cursor,
                                                   int2* __restrict__ ew, int E) {
    int e = blockIdx.x * 256 + threadIdx.x;
    if (e < E) {
        int d = dst[e];
        int s = src[e];
        int pos = atomicAdd(&cursor[d], 1);
        float w = dis[s] * dis[d];
        ew[pos] = make_int2(s, __builtin_bit_cast(int, w));
    }
}

// ---------------------------------------------------------------------------
// Pre-pack W (fp32 [K,N]) into MFMA B-fragment layout, bf16, K zero-padded.
// ---------------------------------------------------------------------------
__global__ __launch_bounds__(256) void pack_w_kernel(const float* __restrict__ W,
                                                     unsigned short* __restrict__ Bp,
                                                     int K, int N, int T) {
    int idx = blockIdx.x * 256 + threadIdx.x;
    int NF = N >> 4;
    int total = T * NF * 64;
    if (idx >= total) return;
    int lane = idx & 63;
    int tnf = idx >> 6;
    int nf = tnf % NF;
    int t = tnf / NF;
    int kbase = t * 32 + (lane >> 4) * 8;
    int n = nf * 16 + (lane & 15);
    unsigned short v[8];
#pragma unroll
    for (int j = 0; j < 8; j++) {
        int k = kbase + j;
        float f = (k < K) ? W[(size_t)k * N + n] : 0.f;
        v[j] = f32_to_bf16(f);
    }
    uint4 p;
    p.x = (unsigned)v[0] | ((unsigned)v[1] << 16);
    p.y = (unsigned)v[2] | ((unsigned)v[3] << 16);
    p.z = (unsigned)v[4] | ((unsigned)v[5] << 16);
    p.w = (unsigned)v[6] | ((unsigned)v[7] << 16);
    *(uint4*)(Bp + (size_t)idx * 8) = p;
}

// ---------------------------------------------------------------------------
// LDS-free MFMA GEMM (round-0 structure), rows/wave parameterized by MF:
// MF m-frags of 16 rows per single-wave block. MF=4 = round-0 exactly.
// MF=2 for GEMM1: 2x the waves (3125, ~3/SIMD) for latency hiding on the
// 200 MB fp32 A-stream; acc VGPRs halve (128->64). B (L2-resident, 128 KB)
// is re-read per wave -- 2x B-reads = +12 us of L2 traffic, negligible.
// Round-5 lesson: NO K-split / NO LDS merge (391 us catastrophe: MfmaUtil
// 1.3%, VGPR 112 < acc size -> serialized inner loop).
// ---------------------------------------------------------------------------
template <int NB, int K, bool ABF16, int MF>
__global__ __launch_bounds__(64) void gemm_mfma(const void* __restrict__ Avoid,
                                                const unsigned short* __restrict__ Bp,
                                                unsigned short* __restrict__ C, int M) {
    constexpr int NF = NB / 16;
    constexpr int FULL = K / 32;
    constexpr int REM = K % 32;
    const int lane = threadIdx.x;
    const int quad = lane >> 4;
    const int mrow = lane & 15;
    const int m_base = blockIdx.x * (16 * MF);

    f32x4 acc[MF][NF];
#pragma unroll
    for (int i = 0; i < MF; i++)
#pragma unroll
        for (int j = 0; j < NF; j++) acc[i][j] = (f32x4)(0.f);

    int c[MF];
#pragma unroll
    for (int i = 0; i < MF; i++) c[i] = min(m_base + i * 16 + mrow, M - 1);  // stores guarded

    const float* Af = (const float*)Avoid;
    const unsigned short* Ah = (const unsigned short*)Avoid;

    for (int t = 0; t < FULL; t++) {
        const int k0 = t * 32 + quad * 8;
        bf16x8 a[MF];
        if (ABF16) {
#pragma unroll
            for (int i = 0; i < MF; i++)
                a[i] = *(const bf16x8*)(Ah + (size_t)c[i] * K + k0);
        } else {
#pragma unroll
            for (int i = 0; i < MF; i++) {
                const float* p = Af + (size_t)c[i] * K + k0;
                float4 x = *(const float4*)p, y = *(const float4*)(p + 4);
                a[i][0] = (short)f32_to_bf16(x.x); a[i][1] = (short)f32_to_bf16(x.y);
                a[i][2] = (short)f32_to_bf16(x.z); a[i][3] = (short)f32_to_bf16(x.w);
                a[i][4] = (short)f32_to_bf16(y.x); a[i][5] = (short)f32_to_bf16(y.y);
                a[i][6] = (short)f32_to_bf16(y.z); a[i][7] = (short)f32_to_bf16(y.w);
            }
        }
#pragma unroll
        for (int nf = 0; nf < NF; nf++) {
            bf16x8 b = *(const bf16x8*)(Bp + (size_t)(t * NF + nf) * 512 + lane * 8);
#pragma unroll
            for (int i = 0; i < MF; i++)
                acc[i][nf] = __builtin_amdgcn_mfma_f32_16x16x32_bf16(a[i], b, acc[i][nf], 0, 0, 0);
        }
    }
    if constexpr (REM > 0) {  // K tail: guarded element loads, B tile zero-padded
        const int kb = FULL * 32 + quad * 8;
        bf16x8 a[MF];
#pragma unroll
        for (int i = 0; i < MF; i++) {
#pragma unroll
            for (int j = 0; j < 8; j++) {
                int k = kb + j;
                float v = 0.f;
                if (k < K)
                    v = ABF16 ? bf16_to_f32(Ah[(size_t)c[i] * K + k]) : Af[(size_t)c[i] * K + k];
                a[i][j] = (short)f32_to_bf16(v);
            }
        }
#pragma unroll
        for (int nf = 0; nf < NF; nf++) {
            bf16x8 b = *(const bf16x8*)(Bp + (size_t)(FULL * NF + nf) * 512 + lane * 8);
#pragma unroll
            for (int i = 0; i < MF; i++)
                acc[i][nf] = __builtin_amdgcn_mfma_f32_16x16x32_bf16(a[i], b, acc[i][nf], 0, 0, 0);
        }
    }

    // epilogue: within m-frag i, D row = quad*4 + ii, col = nf*16 + mrow
#pragma unroll
    for (int i = 0; i < MF; i++)
#pragma unroll
        for (int ii = 0; ii < 4; ii++) {
            const int r = m_base + i * 16 + quad * 4 + ii;
            if (r < M) {
#pragma unroll
                for (int nf = 0; nf < NF; nf++)
                    C[(size_t)r * NB + nf * 16 + mrow] = f32_to_bf16(acc[i][nf][ii]);
            }
        }
}

// ---------------------------------------------------------------------------
// Aggregation v3 (round-0 form, D=128, bf16->bf16): one wave/node, half-wave
// per edge, 16 edges/step: 8 contiguous ew loads in flight, then exec-masked
// row gathers (masked tail halves skip the fetch -> no padding BW waste).
// ---------------------------------------------------------------------------
__global__ __launch_bounds__(256) void aggregate128_v3(const uint2* __restrict__ h,
                                                       const float* __restrict__ dis,
                                                       const int* __restrict__ row_ptr,
                                                       const int2* __restrict__ ew,
                                                       const float* __restrict__ bias,
                                                       uint2* __restrict__ out, int n) {
    const int node = blockIdx.x * 4 + (threadIdx.x >> 6);
    if (node >= n) return;
    const int lane = threadIdx.x & 63;
    const int half = lane >> 5;
    const int c = lane & 31;  // uint2 index in row; channels 4c..4c+3
    const float di = dis[node];
    const int beg = row_ptr[node], end = row_ptr[node + 1];

    float ax0, ax1, ax2, ax3;
    {
        uint2 v = h[(size_t)node * 32 + c];
        float ws = half ? 0.f : di * di;  // self term counted once
        ax0 = ws * blo(v.x); ax1 = ws * bhi(v.x);
        ax2 = ws * blo(v.y); ax3 = ws * bhi(v.y);
    }
    for (int jb = beg; jb < end; jb += 16) {
        int2 p[8];
#pragma unroll
        for (int u = 0; u < 8; u++)
            p[u] = ew[min(jb + half + 2 * u, end - 1)];  // contiguous 8B, tail dup harmless
        float w[8];
        uint2 v[8];
#pragma unroll
        for (int u = 0; u < 8; u++) {
            const bool ok = (jb + half + 2 * u) < end;  // half-uniform -> exec-masked load
            w[u] = ok ? __builtin_bit_cast(float, p[u].y) : 0.f;
            if (ok) v[u] = h[(size_t)p[u].x * 32 + c];
            else    v[u] = make_uint2(0u, 0u);
        }
#pragma unroll
        for (int u = 0; u < 8; u++) {
            ax0 = fmaf(w[u], blo(v[u].x), ax0); ax1 = fmaf(w[u], bhi(v[u].x), ax1);
            ax2 = fmaf(w[u], blo(v[u].y), ax2); ax3 = fmaf(w[u], bhi(v[u].y), ax3);
        }
    }
    ax0 += __shfl_xor(ax0, 32);
    ax1 += __shfl_xor(ax1, 32);
    ax2 += __shfl_xor(ax2, 32);
    ax3 += __shfl_xor(ax3, 32);
    if (half == 0) {
        const float4 b = *(const float4*)(bias + 4 * c);
        uint2 r;
        r.x = (unsigned)f32_to_bf16(fmaxf(ax0 + b.x, 0.f)) |
              ((unsigned)f32_to_bf16(fmaxf(ax1 + b.y, 0.f)) << 16);
        r.y = (unsigned)f32_to_bf16(fmaxf(ax2 + b.z, 0.f)) |
              ((unsigned)f32_to_bf16(fmaxf(ax3 + b.w, 0.f)) << 16);
        out[(size_t)node * 32 + c] = r;
    }
}

// ---------------------------------------------------------------------------
// Aggregation v3 (D=64) with FUSED classifier: after the shuffle reduction the
// post-ReLU 64-ch row is staged in LDS (1 KB/block); lanes 0..9 of each wave
// then compute out[node][cls] = row . Wc[:,cls] + bc directly. Removes the
// separate classifier dispatch and the 51 MB agg2f write+read round-trip.
// NO early return (barrier below); N divisible by 4 so all waves active anyway.
// ---------------------------------------------------------------------------
__global__ __launch_bounds__(256) void aggregate64_cls(const uint2* __restrict__ h,
                                                       const float* __restrict__ dis,
                                                       const int* __restrict__ row_ptr,
                                                       const int2* __restrict__ ew,
                                                       const float* __restrict__ bias,
                                                       const float* __restrict__ Wc,
                                                       const float* __restrict__ bc,
                                                       float* __restrict__ out, int n) {
    __shared__ float sm[4][H2DIM];
    const int wid = threadIdx.x >> 6;
    const int lane = threadIdx.x & 63;
    const int quad = lane >> 4;
    const int c = lane & 15;  // uint2 index in row; channels 4c..4c+3
    const int node = blockIdx.x * 4 + wid;
    const bool active = node < n;
    const int nc = active ? node : n - 1;
    const float di = dis[nc];
    const int beg = row_ptr[nc];
    const int end = active ? row_ptr[nc + 1] : beg;

    float ax0, ax1, ax2, ax3;
    {
        uint2 v = h[(size_t)nc * 16 + c];
        float ws = quad ? 0.f : di * di;
        ax0 = ws * blo(v.x); ax1 = ws * bhi(v.x);
        ax2 = ws * blo(v.y); ax3 = ws * bhi(v.y);
    }
    for (int jb = beg; jb < end; jb += 16) {
        int2 p[4];
#pragma unroll
        for (int u = 0; u < 4; u++)
            p[u] = ew[min(jb + quad + 4 * u, end - 1)];
        float w[4];
        uint2 v[4];
#pragma unroll
        for (int u = 0; u < 4; u++) {
            const bool ok = (jb + quad + 4 * u) < end;  // quad-uniform
            w[u] = ok ? __builtin_bit_cast(float, p[u].y) : 0.f;
            if (ok) v[u] = h[(size_t)p[u].x * 16 + c];
            else    v[u] = make_uint2(0u, 0u);
        }
#pragma unroll
        for (int u = 0; u < 4; u++) {
            ax0 = fmaf(w[u], blo(v[u].x), ax0); ax1 = fmaf(w[u], bhi(v[u].x), ax1);
            ax2 = fmaf(w[u], blo(v[u].y), ax2); ax3 = fmaf(w[u], bhi(v[u].y), ax3);
        }
    }
    ax0 += __shfl_xor(ax0, 16); ax0 += __shfl_xor(ax0, 32);
    ax1 += __shfl_xor(ax1, 16); ax1 += __shfl_xor(ax1, 32);
    ax2 += __shfl_xor(ax2, 16); ax2 += __shfl_xor(ax2, 32);
    ax3 += __shfl_xor(ax3, 16); ax3 += __shfl_xor(ax3, 32);
    if (lane < 16) {
        const float4 b = *(const float4*)(bias + 4 * c);
        sm[wid][4 * c + 0] = fmaxf(ax0 + b.x, 0.f);
        sm[wid][4 * c + 1] = fmaxf(ax1 + b.y, 0.f);
        sm[wid][4 * c + 2] = fmaxf(ax2 + b.z, 0.f);
        sm[wid][4 * c + 3] = fmaxf(ax3 + b.w, 0.f);
    }
    __syncthreads();
    if (active && lane < CDIM) {
        float a2 = bc[lane];
#pragma unroll 8
        for (int k = 0; k < H2DIM; k++) a2 = fmaf(sm[wid][k], Wc[k * CDIM + lane], a2);
        out[(size_t)node * CDIM + lane] = a2;
    }
}

// ---------------------------------------------------------------------------

extern "C" void kernel_launch(void* const* d_in, const int* in_sizes, int n_in,
                              void* d_out, int out_size, void* d_ws, size_t ws_size,
                              hipStream_t stream) {
    const float* x  = (const float*)d_in[0];
    const int*   ei = (const int*)d_in[1];
    const float* W1 = (const float*)d_in[2];
    const float* b1 = (const float*)d_in[3];
    const float* W2 = (const float*)d_in[4];
    const float* b2 = (const float*)d_in[5];
    const float* Wc = (const float*)d_in[6];
    const float* bc = (const float*)d_in[7];
    float* out = (float*)d_out;

    const int N = in_sizes[0] / FDIM;  // 100000
    const int E = in_sizes[1] / 2;     // 1600000
    const int* src = ei;
    const int* dst = ei + E;

    // workspace layout (bytes)
    char* ws = (char*)d_ws;
    int*            cnt    = (int*)(ws + 0x000000);   // N ints (reused as cursor)
    int*            rowptr = (int*)(ws + 0x080000);   // N+1 ints
    float*          dis    = (float*)(ws + 0x100000); // N floats
    int*            bsums  = (int*)(ws + 0x180000);   // ceil(N/256) ints
    int2*           ew     = (int2*)(ws + 0x200000);  // E int2 (12.8 MB)
    unsigned short* W1p    = (unsigned short*)(ws + 0xE40000);  // 128 KB
    unsigned short* W2p    = (unsigned short*)(ws + 0xE80000);  // 16 KB
    unsigned short* h1     = (unsigned short*)(ws + 0xF00000);  // N*128 bf16 (25.6 MB)
    unsigned short* agg1   = (unsigned short*)(ws + 0x2800000); // N*128 bf16 (25.6 MB)
    unsigned short* h2     = (unsigned short*)(ws + 0x4200000); // N*64 bf16 (12.8 MB)

    const int nb = (N + 255) / 256;

    // 1. CSR build + dis + per-edge weights
    hipMemsetAsync(cnt, 0, (size_t)N * sizeof(int), stream);
    hist_kernel<<<(E + 255) / 256, 256, 0, stream>>>(dst, cnt, E);
    block_reduce_kernel<<<nb, 256, 0, stream>>>(cnt, bsums, N);
    scan_sums_kernel<<<1, 512, 0, stream>>>(bsums, nb, rowptr, N);
    scan_blocks_kernel<<<nb, 256, 0, stream>>>(cnt, bsums, rowptr, /*cursor=*/cnt, dis, N);
    fill_kernel<<<(E + 255) / 256, 256, 0, stream>>>(src, dst, dis, /*cursor=*/cnt, ew, E);

    // 2. pack weights to MFMA B-fragment bf16 layout
    pack_w_kernel<<<(16 * 8 * 64 + 255) / 256, 256, 0, stream>>>(W1, W1p, FDIM, H1DIM, 16);
    pack_w_kernel<<<(4 * 4 * 64 + 255) / 256, 256, 0, stream>>>(W2, W2p, H1DIM, H2DIM, 4);

    // 3. layer 1: GEMM (MF=2: 32 rows/wave, 3125 waves) -> agg (+ReLU+bias)
    gemm_mfma<H1DIM, FDIM, false, 2><<<(N + 31) / 32, 64, 0, stream>>>(x, W1p, h1, N);
    aggregate128_v3<<<(N + 3) / 4, 256, 0, stream>>>((const uint2*)h1, dis, rowptr, ew, b1,
                                                     (uint2*)agg1, N);
    // 4. layer 2: GEMM (round-0 form, MF=4) -> agg (+ReLU+bias) + fused classifier
    gemm_mfma<H2DIM, H1DIM, true, 4><<<(N + 63) / 64, 64, 0, stream>>>(agg1, W2p, h2, N);
    aggregate64_cls<<<(N + 3) / 4, 256, 0, stream>>>((const uint2*)h2, dis, rowptr, ew, b2,
                                                     Wc, bc, out, N);
}

// Round 7
// 637.212 us; speedup vs baseline: 1.5801x; 1.0153x over previous
//
#include <hip/hip_runtime.h>

// Problem constants (from reference setup_inputs)
#define FDIM 500
#define H1DIM 128
#define H2DIM 64
#define CDIM 10

using f32x4 = __attribute__((ext_vector_type(4))) float;
using bf16x8 = __attribute__((ext_vector_type(8))) short;  // 8 bf16 in 4 VGPRs

__device__ __forceinline__ unsigned short f32_to_bf16(float f) {
    unsigned u = __builtin_bit_cast(unsigned, f);
    u += 0x7FFFu + ((u >> 16) & 1u);  // RNE (inputs are finite, no NaN handling)
    return (unsigned short)(u >> 16);
}
__device__ __forceinline__ float bf16_to_f32(unsigned short h) {
    return __builtin_bit_cast(float, (unsigned)h << 16);
}
__device__ __forceinline__ float blo(unsigned u) {
    return __builtin_bit_cast(float, u << 16);
}
__device__ __forceinline__ float bhi(unsigned u) {
    return __builtin_bit_cast(float, u & 0xFFFF0000u);
}

// ---------------------------------------------------------------------------
// CSR build: histogram -> two-level scan -> atomic-cursor fill. dis = rsqrt(deg+1)
// folded into scan_blocks. fill precomputes ew[pos] = {src, dis[src]*dis[dst]}.
// ---------------------------------------------------------------------------

__device__ __forceinline__ void pack_w_body(const float* __restrict__ W,
                                            unsigned short* __restrict__ Bp,
                                            int K, int N, int T, int idx) {
    int NF = N >> 4;
    int total = T * NF * 64;
    if (idx >= total) return;
    int lane = idx & 63;
    int tnf = idx >> 6;
    int nf = tnf % NF;
    int t = tnf / NF;
    int kbase = t * 32 + (lane >> 4) * 8;
    int n = nf * 16 + (lane & 15);
    unsigned short v[8];
#pragma unroll
    for (int j = 0; j < 8; j++) {
        int k = kbase + j;
        float f = (k < K) ? W[(size_t)k * N + n] : 0.f;
        v[j] = f32_to_bf16(f);
    }
    uint4 p;
    p.x = (unsigned)v[0] | ((unsigned)v[1] << 16);
    p.y = (unsigned)v[2] | ((unsigned)v[3] << 16);
    p.z = (unsigned)v[4] | ((unsigned)v[5] << 16);
    p.w = (unsigned)v[6] | ((unsigned)v[7] << 16);
    *(uint4*)(Bp + (size_t)idx * 8) = p;
}

// hist + pack_w1 + pack_w2 are mutually independent -> one block-range-
// partitioned dispatch (saves 2 launch/drain slots; bodies unchanged).
__global__ __launch_bounds__(256) void prep_kernel(const int* __restrict__ dst,
                                                   int* __restrict__ cnt, int E,
                                                   const float* __restrict__ W1,
                                                   unsigned short* __restrict__ W1p,
                                                   const float* __restrict__ W2,
                                                   unsigned short* __restrict__ W2p) {
    const int nbE = (E + 255) >> 8;
    const int b = blockIdx.x;
    if (b < nbE) {
        int e = b * 256 + threadIdx.x;
        if (e < E) atomicAdd(&cnt[dst[e]], 1);
    } else if (b < nbE + 32) {  // W1 pack: 16 tiles * 8 nf * 64 lanes = 8192 threads
        pack_w_body(W1, W1p, FDIM, H1DIM, 16, (b - nbE) * 256 + threadIdx.x);
    } else {  // W2 pack: 4 tiles * 4 nf * 64 lanes = 1024 threads
        pack_w_body(W2, W2p, H1DIM, H2DIM, 4, (b - nbE - 32) * 256 + threadIdx.x);
    }
}

__global__ __launch_bounds__(256) void block_reduce_kernel(const int* __restrict__ cnt,
                                                           int* __restrict__ bsums, int n) {
    __shared__ int s[256];
    int i = blockIdx.x * 256 + threadIdx.x;
    s[threadIdx.x] = (i < n) ? cnt[i] : 0;
    __syncthreads();
    for (int o = 128; o > 0; o >>= 1) {
        if (threadIdx.x < o) s[threadIdx.x] += s[threadIdx.x + o];
        __syncthreads();
    }
    if (threadIdx.x == 0) bsums[blockIdx.x] = s[0];
}

__global__ __launch_bounds__(512) void scan_sums_kernel(int* __restrict__ bsums, int nb,
                                                        int* __restrict__ row_ptr, int n) {
    __shared__ int s[512];
    int v = (threadIdx.x < nb) ? bsums[threadIdx.x] : 0;
    s[threadIdx.x] = v;
    __syncthreads();
    for (int o = 1; o < 512; o <<= 1) {
        int t = (threadIdx.x >= o) ? s[threadIdx.x - o] : 0;
        __syncthreads();
        s[threadIdx.x] += t;
        __syncthreads();
    }
    if (threadIdx.x < nb) bsums[threadIdx.x] = s[threadIdx.x] - v;  // exclusive
    if (threadIdx.x == 511) row_ptr[n] = s[511];                    // total == E
}

// scan_blocks also computes dis = rsqrt(deg+1) (folds the old dis_kernel).
__global__ __launch_bounds__(256) void scan_blocks_kernel(const int* __restrict__ cnt,
                                                          const int* __restrict__ bsums,
                                                          int* __restrict__ row_ptr,
                                                          int* __restrict__ cursor,
                                                          float* __restrict__ dis, int n) {
    __shared__ int s[256];
    int i = blockIdx.x * 256 + threadIdx.x;
    int v = (i < n) ? cnt[i] : 0;
    s[threadIdx.x] = v;
    __syncthreads();
    for (int o = 1; o < 256; o <<= 1) {
        int t = (threadIdx.x >= o) ? s[threadIdx.x - o] : 0;
        __syncthreads();
        s[threadIdx.x] += t;
        __syncthreads();
    }
    int excl = s[threadIdx.x] - v + bsums[blockIdx.x];
    if (i < n) {
        row_ptr[i] = excl;
        cursor[i] = excl;
        dis[i] = rsqrtf((float)v + 1.0f);  // +1 self loop
    }
}

__global__ __launch_bounds__(256) void fill_kernel(const int* __restrict__ src,
                                                   const int* __restrict__ dst,
                                                   const float* __restrict__ dis,
                                                   int* __restrict__ cursor,
                                                   int2* __restrict__ ew, int E) {
    int e = blockIdx.x * 256 + threadIdx.x;
    if (e < E) {
        int d = dst[e];
        int s = src[e];
        int pos = atomicAdd(&cursor[d], 1);
        float w = dis[s] * dis[d];
        ew[pos] = make_int2(s, __builtin_bit_cast(int, w));
    }
}

// ---------------------------------------------------------------------------
// LDS-free MFMA GEMM (round-0 structure), rows/wave parameterized by MF.
// MF=4 is the round-0 config and the best measured for BOTH layers:
// r5/r6 A/B isolated T(gemm1,MF=2)=109us vs T(gemm1,MF=4)=71us -- halving
// rows/wave halves MFMAs per B-load (same 8 L2 B-loads per K-step), so the
// per-wave B-latency stall dominates; more waves didn't compensate.
// Round-5 lesson: NO K-split / NO LDS merge (391us: MfmaUtil 1.3%).
// ---------------------------------------------------------------------------
template <int NB, int K, bool ABF16, int MF>
__global__ __launch_bounds__(64) void gemm_mfma(const void* __restrict__ Avoid,
                                                const unsigned short* __restrict__ Bp,
                                                unsigned short* __restrict__ C, int M) {
    constexpr int NF = NB / 16;
    constexpr int FULL = K / 32;
    constexpr int REM = K % 32;
    const int lane = threadIdx.x;
    const int quad = lane >> 4;
    const int mrow = lane & 15;
    const int m_base = blockIdx.x * (16 * MF);

    f32x4 acc[MF][NF];
#pragma unroll
    for (int i = 0; i < MF; i++)
#pragma unroll
        for (int j = 0; j < NF; j++) acc[i][j] = (f32x4)(0.f);

    int c[MF];
#pragma unroll
    for (int i = 0; i < MF; i++) c[i] = min(m_base + i * 16 + mrow, M - 1);  // stores guarded

    const float* Af = (const float*)Avoid;
    const unsigned short* Ah = (const unsigned short*)Avoid;

    for (int t = 0; t < FULL; t++) {
        const int k0 = t * 32 + quad * 8;
        bf16x8 a[MF];
        if (ABF16) {
#pragma unroll
            for (int i = 0; i < MF; i++)
                a[i] = *(const bf16x8*)(Ah + (size_t)c[i] * K + k0);
        } else {
#pragma unroll
            for (int i = 0; i < MF; i++) {
                const float* p = Af + (size_t)c[i] * K + k0;
                float4 x = *(const float4*)p, y = *(const float4*)(p + 4);
                a[i][0] = (short)f32_to_bf16(x.x); a[i][1] = (short)f32_to_bf16(x.y);
                a[i][2] = (short)f32_to_bf16(x.z); a[i][3] = (short)f32_to_bf16(x.w);
                a[i][4] = (short)f32_to_bf16(y.x); a[i][5] = (short)f32_to_bf16(y.y);
                a[i][6] = (short)f32_to_bf16(y.z); a[i][7] = (short)f32_to_bf16(y.w);
            }
        }
#pragma unroll
        for (int nf = 0; nf < NF; nf++) {
            bf16x8 b = *(const bf16x8*)(Bp + (size_t)(t * NF + nf) * 512 + lane * 8);
#pragma unroll
            for (int i = 0; i < MF; i++)
                acc[i][nf] = __builtin_amdgcn_mfma_f32_16x16x32_bf16(a[i], b, acc[i][nf], 0, 0, 0);
        }
    }
    if constexpr (REM > 0) {  // K tail: guarded element loads, B tile zero-padded
        const int kb = FULL * 32 + quad * 8;
        bf16x8 a[MF];
#pragma unroll
        for (int i = 0; i < MF; i++) {
#pragma unroll
            for (int j = 0; j < 8; j++) {
                int k = kb + j;
                float v = 0.f;
                if (k < K)
                    v = ABF16 ? bf16_to_f32(Ah[(size_t)c[i] * K + k]) : Af[(size_t)c[i] * K + k];
                a[i][j] = (short)f32_to_bf16(v);
            }
        }
#pragma unroll
        for (int nf = 0; nf < NF; nf++) {
            bf16x8 b = *(const bf16x8*)(Bp + (size_t)(FULL * NF + nf) * 512 + lane * 8);
#pragma unroll
            for (int i = 0; i < MF; i++)
                acc[i][nf] = __builtin_amdgcn_mfma_f32_16x16x32_bf16(a[i], b, acc[i][nf], 0, 0, 0);
        }
    }

    // epilogue: within m-frag i, D row = quad*4 + ii, col = nf*16 + mrow
#pragma unroll
    for (int i = 0; i < MF; i++)
#pragma unroll
        for (int ii = 0; ii < 4; ii++) {
            const int r = m_base + i * 16 + quad * 4 + ii;
            if (r < M) {
#pragma unroll
                for (int nf = 0; nf < NF; nf++)
                    C[(size_t)r * NB + nf * 16 + mrow] = f32_to_bf16(acc[i][nf][ii]);
            }
        }
}

// ---------------------------------------------------------------------------
// Aggregation v3 (round-0 form, D=128, bf16->bf16): one wave/node, half-wave
// per edge, 16 edges/step: 8 contiguous ew loads in flight, then exec-masked
// row gathers (masked tail halves skip the fetch -> no padding BW waste).
// ---------------------------------------------------------------------------
__global__ __launch_bounds__(256) void aggregate128_v3(const uint2* __restrict__ h,
                                                       const float* __restrict__ dis,
                                                       const int* __restrict__ row_ptr,
                                                       const int2* __restrict__ ew,
                                                       const float* __restrict__ bias,
                                                       uint2* __restrict__ out, int n) {
    const int node = blockIdx.x * 4 + (threadIdx.x >> 6);
    if (node >= n) return;
    const int lane = threadIdx.x & 63;
    const int half = lane >> 5;
    const int c = lane & 31;  // uint2 index in row; channels 4c..4c+3
    const float di = dis[node];
    const int beg = row_ptr[node], end = row_ptr[node + 1];

    float ax0, ax1, ax2, ax3;
    {
        uint2 v = h[(size_t)node * 32 + c];
        float ws = half ? 0.f : di * di;  // self term counted once
        ax0 = ws * blo(v.x); ax1 = ws * bhi(v.x);
        ax2 = ws * blo(v.y); ax3 = ws * bhi(v.y);
    }
    for (int jb = beg; jb < end; jb += 16) {
        int2 p[8];
#pragma unroll
        for (int u = 0; u < 8; u++)
            p[u] = ew[min(jb + half + 2 * u, end - 1)];  // contiguous 8B, tail dup harmless
        float w[8];
        uint2 v[8];
#pragma unroll
        for (int u = 0; u < 8; u++) {
            const bool ok = (jb + half + 2 * u) < end;  // half-uniform -> exec-masked load
            w[u] = ok ? __builtin_bit_cast(float, p[u].y) : 0.f;
            if (ok) v[u] = h[(size_t)p[u].x * 32 + c];
            else    v[u] = make_uint2(0u, 0u);
        }
#pragma unroll
        for (int u = 0; u < 8; u++) {
            ax0 = fmaf(w[u], blo(v[u].x), ax0); ax1 = fmaf(w[u], bhi(v[u].x), ax1);
            ax2 = fmaf(w[u], blo(v[u].y), ax2); ax3 = fmaf(w[u], bhi(v[u].y), ax3);
        }
    }
    ax0 += __shfl_xor(ax0, 32);
    ax1 += __shfl_xor(ax1, 32);
    ax2 += __shfl_xor(ax2, 32);
    ax3 += __shfl_xor(ax3, 32);
    if (half == 0) {
        const float4 b = *(const float4*)(bias + 4 * c);
        uint2 r;
        r.x = (unsigned)f32_to_bf16(fmaxf(ax0 + b.x, 0.f)) |
              ((unsigned)f32_to_bf16(fmaxf(ax1 + b.y, 0.f)) << 16);
        r.y = (unsigned)f32_to_bf16(fmaxf(ax2 + b.z, 0.f)) |
              ((unsigned)f32_to_bf16(fmaxf(ax3 + b.w, 0.f)) << 16);
        out[(size_t)node * 32 + c] = r;
    }
}

// ---------------------------------------------------------------------------
// Aggregation v3 (D=64) with FUSED classifier: after the shuffle reduction the
// post-ReLU 64-ch row is staged in LDS (1 KB/block); lanes 0..9 of each wave
// then compute out[node][cls] = row . Wc[:,cls] + bc directly. Removes the
// separate classifier dispatch and the 51 MB agg2f write+read round-trip.
// NO early return (barrier below); N divisible by 4 so all waves active anyway.
// ---------------------------------------------------------------------------
__global__ __launch_bounds__(256) void aggregate64_cls(const uint2* __restrict__ h,
                                                       const float* __restrict__ dis,
                                                       const int* __restrict__ row_ptr,
                                                       const int2* __restrict__ ew,
                                                       const float* __restrict__ bias,
                                                       const float* __restrict__ Wc,
                                                       const float* __restrict__ bc,
                                                       float* __restrict__ out, int n) {
    __shared__ float sm[4][H2DIM];
    const int wid = threadIdx.x >> 6;
    const int lane = threadIdx.x & 63;
    const int quad = lane >> 4;
    const int c = lane & 15;  // uint2 index in row; channels 4c..4c+3
    const int node = blockIdx.x * 4 + wid;
    const bool active = node < n;
    const int nc = active ? node : n - 1;
    const float di = dis[nc];
    const int beg = row_ptr[nc];
    const int end = active ? row_ptr[nc + 1] : beg;

    float ax0, ax1, ax2, ax3;
    {
        uint2 v = h[(size_t)nc * 16 + c];
        float ws = quad ? 0.f : di * di;
        ax0 = ws * blo(v.x); ax1 = ws * bhi(v.x);
        ax2 = ws * blo(v.y); ax3 = ws * bhi(v.y);
    }
    for (int jb = beg; jb < end; jb += 16) {
        int2 p[4];
#pragma unroll
        for (int u = 0; u < 4; u++)
            p[u] = ew[min(jb + quad + 4 * u, end - 1)];
        float w[4];
        uint2 v[4];
#pragma unroll
        for (int u = 0; u < 4; u++) {
            const bool ok = (jb + quad + 4 * u) < end;  // quad-uniform
            w[u] = ok ? __builtin_bit_cast(float, p[u].y) : 0.f;
            if (ok) v[u] = h[(size_t)p[u].x * 16 + c];
            else    v[u] = make_uint2(0u, 0u);
        }
#pragma unroll
        for (int u = 0; u < 4; u++) {
            ax0 = fmaf(w[u], blo(v[u].x), ax0); ax1 = fmaf(w[u], bhi(v[u].x), ax1);
            ax2 = fmaf(w[u], blo(v[u].y), ax2); ax3 = fmaf(w[u], bhi(v[u].y), ax3);
        }
    }
    ax0 += __shfl_xor(ax0, 16); ax0 += __shfl_xor(ax0, 32);
    ax1 += __shfl_xor(ax1, 16); ax1 += __shfl_xor(ax1, 32);
    ax2 += __shfl_xor(ax2, 16); ax2 += __shfl_xor(ax2, 32);
    ax3 += __shfl_xor(ax3, 16); ax3 += __shfl_xor(ax3, 32);
    if (lane < 16) {
        const float4 b = *(const float4*)(bias + 4 * c);
        sm[wid][4 * c + 0] = fmaxf(ax0 + b.x, 0.f);
        sm[wid][4 * c + 1] = fmaxf(ax1 + b.y, 0.f);
        sm[wid][4 * c + 2] = fmaxf(ax2 + b.z, 0.f);
        sm[wid][4 * c + 3] = fmaxf(ax3 + b.w, 0.f);
    }
    __syncthreads();
    if (active && lane < CDIM) {
        float a2 = bc[lane];
#pragma unroll 8
        for (int k = 0; k < H2DIM; k++) a2 = fmaf(sm[wid][k], Wc[k * CDIM + lane], a2);
        out[(size_t)node * CDIM + lane] = a2;
    }
}

// ---------------------------------------------------------------------------

extern "C" void kernel_launch(void* const* d_in, const int* in_sizes, int n_in,
                              void* d_out, int out_size, void* d_ws, size_t ws_size,
                              hipStream_t stream) {
    const float* x  = (const float*)d_in[0];
    const int*   ei = (const int*)d_in[1];
    const float* W1 = (const float*)d_in[2];
    const float* b1 = (const float*)d_in[3];
    const float* W2 = (const float*)d_in[4];
    const float* b2 = (const float*)d_in[5];
    const float* Wc = (const float*)d_in[6];
    const float* bc = (const float*)d_in[7];
    float* out = (float*)d_out;

    const int N = in_sizes[0] / FDIM;  // 100000
    const int E = in_sizes[1] / 2;     // 1600000
    const int* src = ei;
    const int* dst = ei + E;

    // workspace layout (bytes)
    char* ws = (char*)d_ws;
    int*            cnt    = (int*)(ws + 0x000000);   // N ints (reused as cursor)
    int*            rowptr = (int*)(ws + 0x080000);   // N+1 ints
    float*          dis    = (float*)(ws + 0x100000); // N floats
    int*            bsums  = (int*)(ws + 0x180000);   // ceil(N/256) ints
    int2*           ew     = (int2*)(ws + 0x200000);  // E int2 (12.8 MB)
    unsigned short* W1p    = (unsigned short*)(ws + 0xE40000);  // 128 KB
    unsigned short* W2p    = (unsigned short*)(ws + 0xE80000);  // 16 KB
    unsigned short* h1     = (unsigned short*)(ws + 0xF00000);  // N*128 bf16 (25.6 MB)
    unsigned short* agg1   = (unsigned short*)(ws + 0x2800000); // N*128 bf16 (25.6 MB)
    unsigned short* h2     = (unsigned short*)(ws + 0x4200000); // N*64 bf16 (12.8 MB)

    const int nb = (N + 255) / 256;
    const int nbE = (E + 255) / 256;

    // 1. CSR build (hist merged with weight packing) + dis + per-edge weights
    hipMemsetAsync(cnt, 0, (size_t)N * sizeof(int), stream);
    prep_kernel<<<nbE + 32 + 4, 256, 0, stream>>>(dst, cnt, E, W1, W1p, W2, W2p);
    block_reduce_kernel<<<nb, 256, 0, stream>>>(cnt, bsums, N);
    scan_sums_kernel<<<1, 512, 0, stream>>>(bsums, nb, rowptr, N);
    scan_blocks_kernel<<<nb, 256, 0, stream>>>(cnt, bsums, rowptr, /*cursor=*/cnt, dis, N);
    fill_kernel<<<nbE, 256, 0, stream>>>(src, dst, dis, /*cursor=*/cnt, ew, E);

    // 2. layer 1: GEMM (MF=4, round-0 config: measured ~71us vs 109 at MF=2)
    gemm_mfma<H1DIM, FDIM, false, 4><<<(N + 63) / 64, 64, 0, stream>>>(x, W1p, h1, N);
    aggregate128_v3<<<(N + 3) / 4, 256, 0, stream>>>((const uint2*)h1, dis, rowptr, ew, b1,
                                                     (uint2*)agg1, N);
    // 3. layer 2: GEMM (MF=4) -> agg (+ReLU+bias) with fused classifier
    gemm_mfma<H2DIM, H1DIM, true, 4><<<(N + 63) / 64, 64, 0, stream>>>(agg1, W2p, h2, N);
    aggregate64_cls<<<(N + 3) / 4, 256, 0, stream>>>((const uint2*)h2, dis, rowptr, ew, b2,
                                                     Wc, bc, out, N);
}